// Round 1
// baseline (827.785 us; speedup 1.0000x reference)
//
#include <hip/hip_runtime.h>
#include <math.h>

#define N_NODES 100000
#define NNZ_E   3200000
#define NFEAT   512
#define NHID    256
#define NCLASS  41
#define NC_PAD  48

typedef __attribute__((ext_vector_type(8))) short   short8;   // 8 bf16 (4 VGPRs)
typedef __attribute__((ext_vector_type(8))) unsigned short ushort8;
typedef __attribute__((ext_vector_type(4))) float   f32x4;

// ---- bf16 helpers ----
__device__ __forceinline__ unsigned short f2bf(float f) {
    unsigned u = __builtin_bit_cast(unsigned, f);
    unsigned r = u + 0x7fffu + ((u >> 16) & 1u);   // RNE
    return (unsigned short)(r >> 16);
}
__device__ __forceinline__ float bf2f(unsigned short b) {
    return __builtin_bit_cast(float, (unsigned)b << 16);
}

// ---------------------------------------------------------------------------
// K0: w1t = bf16(w1^T) [256][512];  w2t = bf16(w2^T zero-padded) [48][256]
// ---------------------------------------------------------------------------
__global__ void prep_w_kernel(const float* __restrict__ w1, const float* __restrict__ w2,
                              unsigned short* __restrict__ w1t, unsigned short* __restrict__ w2t) {
    int tid = blockIdx.x * 256 + threadIdx.x;
    if (tid < NHID * NFEAT) {                     // 256*512
        int n = tid >> 9, k = tid & 511;
        w1t[tid] = f2bf(w1[k * NHID + n]);
    }
    int t2 = tid - NHID * NFEAT;
    if (t2 >= 0 && t2 < NC_PAD * NHID) {          // 48*256
        int n = t2 >> 8, k = t2 & 255;
        w2t[t2] = (n < NCLASS) ? f2bf(w2[k * NCLASS + n]) : (unsigned short)0;
    }
}

// ---------------------------------------------------------------------------
// K1: CSR row_ptr from sorted adj_rows (lower_bound per row)
// ---------------------------------------------------------------------------
__global__ void rowptr_kernel(const int* __restrict__ rows, int* __restrict__ row_ptr) {
    int r = blockIdx.x * 256 + threadIdx.x;
    if (r > N_NODES) return;
    int lo = 0, hi = NNZ_E;
    while (lo < hi) {
        int mid = (lo + hi) >> 1;
        if (rows[mid] < r) lo = mid + 1; else hi = mid;
    }
    row_ptr[r] = lo;
}

// ---------------------------------------------------------------------------
// K2: XW = x @ w1  (bf16 MFMA, fp32 acc) -> xw bf16 [N,256]
// Block: 256 thr = 4 waves; block tile 64 rows x 256 cols; BK=32.
// Wave w covers cols w*64..w*64+63 as 4x4 grid of 16x16x32 MFMA tiles.
// ---------------------------------------------------------------------------
__global__ __launch_bounds__(256) void gemm1_kernel(const float* __restrict__ x,
                                                    const unsigned short* __restrict__ w1t,
                                                    unsigned short* __restrict__ xw) {
    __shared__ unsigned short As[64][40];    // pad 32->40 (2-way bank alias = free)
    __shared__ unsigned short Bs[256][40];   // [n][k], k-contiguous for B-frag reads

    const int rb   = blockIdx.x * 64;
    const int tid  = threadIdx.x;
    const int wave = tid >> 6;
    const int lane = tid & 63;
    const int l15  = lane & 15;
    const int quad = lane >> 4;

    f32x4 acc[4][4] = {};

    // A staging coords: thread t -> row t>>2, k-offset (t&3)*8
    int ar = tid >> 2;
    int ako = (tid & 3) * 8;
    int arow = rb + ar; if (arow >= N_NODES) arow = N_NODES - 1;
    const float* asrc_base = x + (long)arow * NFEAT + ako;

    for (int kc = 0; kc < NFEAT; kc += 32) {
        // ---- stage A: 64x32 fp32 -> bf16 LDS ----
        {
            const float* s = asrc_base + kc;
            float4 f0 = *(const float4*)(s);
            float4 f1 = *(const float4*)(s + 4);
            ushort8 v;
            v[0] = f2bf(f0.x); v[1] = f2bf(f0.y); v[2] = f2bf(f0.z); v[3] = f2bf(f0.w);
            v[4] = f2bf(f1.x); v[5] = f2bf(f1.y); v[6] = f2bf(f1.z); v[7] = f2bf(f1.w);
            *(ushort8*)&As[ar][ako] = v;
        }
        // ---- stage B: w1t[n][kc..kc+31] -> Bs[n][0..31], thread t = n ----
        {
            const ushort8* s = (const ushort8*)(w1t + (long)tid * NFEAT + kc);
            *(ushort8*)&Bs[tid][0]  = s[0];
            *(ushort8*)&Bs[tid][8]  = s[1];
            *(ushort8*)&Bs[tid][16] = s[2];
            *(ushort8*)&Bs[tid][24] = s[3];
        }
        __syncthreads();

        short8 a[4];
#pragma unroll
        for (int mt = 0; mt < 4; mt++)
            a[mt] = *(const short8*)&As[mt * 16 + l15][quad * 8];
#pragma unroll
        for (int nt = 0; nt < 4; nt++) {
            short8 b = *(const short8*)&Bs[wave * 64 + nt * 16 + l15][quad * 8];
#pragma unroll
            for (int mt = 0; mt < 4; mt++)
                acc[mt][nt] = __builtin_amdgcn_mfma_f32_16x16x32_bf16(a[mt], b, acc[mt][nt], 0, 0, 0);
        }
        __syncthreads();
    }

    // epilogue: C/D layout col=lane&15, row=quad*4+reg
#pragma unroll
    for (int mt = 0; mt < 4; mt++) {
#pragma unroll
        for (int nt = 0; nt < 4; nt++) {
            int col = wave * 64 + nt * 16 + l15;
#pragma unroll
            for (int r = 0; r < 4; r++) {
                int row = rb + mt * 16 + quad * 4 + r;
                if (row < N_NODES)
                    xw[(long)row * NHID + col] = f2bf(acc[mt][nt][r]);
            }
        }
    }
}

// ---------------------------------------------------------------------------
// K3: h = relu(spmm(A, xw) + b1) -> bf16 [N,256].  One wave per row.
// ---------------------------------------------------------------------------
__global__ __launch_bounds__(256) void spmm1_kernel(const unsigned short* __restrict__ xw,
                                                    const int* __restrict__ row_ptr,
                                                    const int* __restrict__ cols,
                                                    const float* __restrict__ vals,
                                                    const float* __restrict__ b1,
                                                    unsigned short* __restrict__ h) {
    int row = blockIdx.x * 4 + (threadIdx.x >> 6);
    if (row >= N_NODES) return;
    int lane = threadIdx.x & 63;
    int e0 = row_ptr[row], e1 = row_ptr[row + 1];

    float a0 = 0.f, a1 = 0.f, a2 = 0.f, a3 = 0.f;
    for (int base = e0; base < e1; base += 64) {
        int   myc = 0;
        float myv = 0.f;
        int idx = base + lane;
        if (idx < e1) { myc = cols[idx]; myv = vals[idx]; }
        int cnt = e1 - base; if (cnt > 64) cnt = 64;
        for (int j = 0; j < cnt; j++) {
            int   c = __shfl(myc, j);
            float v = __shfl(myv, j);
            uint2 q = *(const uint2*)(xw + (long)c * NHID + lane * 4);
            a0 += v * __builtin_bit_cast(float, q.x << 16);
            a1 += v * __builtin_bit_cast(float, q.x & 0xffff0000u);
            a2 += v * __builtin_bit_cast(float, q.y << 16);
            a3 += v * __builtin_bit_cast(float, q.y & 0xffff0000u);
        }
    }
    float4 bv = *(const float4*)(b1 + lane * 4);
    a0 = fmaxf(a0 + bv.x, 0.f);
    a1 = fmaxf(a1 + bv.y, 0.f);
    a2 = fmaxf(a2 + bv.z, 0.f);
    a3 = fmaxf(a3 + bv.w, 0.f);
    uint2 o;
    o.x = (unsigned)f2bf(a0) | ((unsigned)f2bf(a1) << 16);
    o.y = (unsigned)f2bf(a2) | ((unsigned)f2bf(a3) << 16);
    *(uint2*)(h + (long)row * NHID + lane * 4) = o;
}

// ---------------------------------------------------------------------------
// K4: p = h @ w2  (bf16 MFMA) -> fp32 [N,48].  One wave per 16-row tile.
// ---------------------------------------------------------------------------
__global__ __launch_bounds__(256) void gemm2_kernel(const unsigned short* __restrict__ h,
                                                    const unsigned short* __restrict__ w2t,
                                                    float* __restrict__ p) {
    int rt = blockIdx.x * 4 + (threadIdx.x >> 6);
    int row0 = rt * 16;
    if (row0 >= N_NODES) return;
    int lane = threadIdx.x & 63;
    int l15 = lane & 15, quad = lane >> 4;

    int arow = row0 + l15; if (arow >= N_NODES) arow = N_NODES - 1;
    f32x4 acc[3] = {};
#pragma unroll
    for (int kc = 0; kc < NHID; kc += 32) {
        short8 a = *(const short8*)(h + (long)arow * NHID + kc + quad * 8);
#pragma unroll
        for (int nt = 0; nt < 3; nt++) {
            short8 b = *(const short8*)(w2t + (long)(nt * 16 + l15) * NHID + kc + quad * 8);
            acc[nt] = __builtin_amdgcn_mfma_f32_16x16x32_bf16(a, b, acc[nt], 0, 0, 0);
        }
    }
#pragma unroll
    for (int nt = 0; nt < 3; nt++) {
        int col = nt * 16 + l15;
#pragma unroll
        for (int r = 0; r < 4; r++) {
            int row = row0 + quad * 4 + r;
            if (row < N_NODES)
                p[(long)row * NC_PAD + col] = acc[nt][r];
        }
    }
}

// ---------------------------------------------------------------------------
// K5: out = log_softmax(spmm(A, p) + b2).  One wave per row; lane = class.
// ---------------------------------------------------------------------------
__global__ __launch_bounds__(256) void spmm2_kernel(const float* __restrict__ p,
                                                    const int* __restrict__ row_ptr,
                                                    const int* __restrict__ cols,
                                                    const float* __restrict__ vals,
                                                    const float* __restrict__ b2,
                                                    float* __restrict__ out) {
    int row = blockIdx.x * 4 + (threadIdx.x >> 6);
    if (row >= N_NODES) return;
    int lane = threadIdx.x & 63;
    int e0 = row_ptr[row], e1 = row_ptr[row + 1];

    float acc = 0.f;
    for (int base = e0; base < e1; base += 64) {
        int   myc = 0;
        float myv = 0.f;
        int idx = base + lane;
        if (idx < e1) { myc = cols[idx]; myv = vals[idx]; }
        int cnt = e1 - base; if (cnt > 64) cnt = 64;
        for (int j = 0; j < cnt; j++) {
            int   c = __shfl(myc, j);
            float v = __shfl(myv, j);
            if (lane < NC_PAD) acc += v * p[(long)c * NC_PAD + lane];
        }
    }
    float logit = (lane < NCLASS) ? acc + b2[lane] : -__builtin_inff();
    float m = logit;
#pragma unroll
    for (int s = 32; s; s >>= 1) m = fmaxf(m, __shfl_xor(m, s));
    float e = (lane < NCLASS) ? __expf(logit - m) : 0.f;
    float sum = e;
#pragma unroll
    for (int s = 32; s; s >>= 1) sum += __shfl_xor(sum, s);
    float lsm = logit - m - __logf(sum);
    if (lane < NCLASS) out[(long)row * NCLASS + lane] = lsm;
}

// ---------------------------------------------------------------------------
extern "C" void kernel_launch(void* const* d_in, const int* in_sizes, int n_in,
                              void* d_out, int out_size, void* d_ws, size_t ws_size,
                              hipStream_t stream) {
    const float* x        = (const float*)d_in[0];
    const int*   adj_rows = (const int*)  d_in[1];
    const int*   adj_cols = (const int*)  d_in[2];
    const float* adj_vals = (const float*)d_in[3];
    const float* w1       = (const float*)d_in[4];
    const float* b1       = (const float*)d_in[5];
    const float* w2       = (const float*)d_in[6];
    const float* b2       = (const float*)d_in[7];
    float* out = (float*)d_out;

    // workspace layout (bytes)
    char* ws = (char*)d_ws;
    unsigned short* w1t     = (unsigned short*)(ws);                      // 262144
    unsigned short* w2t     = (unsigned short*)(ws + 0x40000);            // 24576
    int*            row_ptr = (int*)           (ws + 0x46000);            // 400004
    unsigned short* xw      = (unsigned short*)(ws + 0xA8000);            // 51.2 MB (bf16 [N,256])
    unsigned short* hbuf    = (unsigned short*)(ws + 0xA8000 + 51200000L);// 51.2 MB (bf16 [N,256])
    float*          p       = (float*)         (ws + 0xA8000);            // aliases xw (dead after K3)

    prep_w_kernel<<<(NHID * NFEAT + NC_PAD * NHID + 255) / 256, 256, 0, stream>>>(w1, w2, w1t, w2t);
    rowptr_kernel<<<(N_NODES + 1 + 255) / 256, 256, 0, stream>>>(adj_rows, row_ptr);
    gemm1_kernel<<<(N_NODES + 63) / 64, 256, 0, stream>>>(x, w1t, xw);
    spmm1_kernel<<<(N_NODES + 3) / 4, 256, 0, stream>>>(xw, row_ptr, adj_cols, adj_vals, b1, hbuf);
    gemm2_kernel<<<((N_NODES + 15) / 16 + 3) / 4, 256, 0, stream>>>(hbuf, w2t, p);
    spmm2_kernel<<<(N_NODES + 3) / 4, 256, 0, stream>>>(p, row_ptr, adj_cols, adj_vals, b2, out);
}

// Round 2
// 695.577 us; speedup vs baseline: 1.1901x; 1.1901x over previous
//
#include <hip/hip_runtime.h>
#include <math.h>

#define N_NODES 100000
#define NNZ_E   3200000
#define NFEAT   512
#define NHID    256
#define NCLASS  41
#define NC_PAD  48

typedef __attribute__((ext_vector_type(8))) short   short8;   // 8 bf16 (4 VGPRs)
typedef __attribute__((ext_vector_type(8))) unsigned short ushort8;
typedef __attribute__((ext_vector_type(4))) float   f32x4;

// ---- bf16 helpers ----
__device__ __forceinline__ unsigned short f2bf(float f) {
    unsigned u = __builtin_bit_cast(unsigned, f);
    unsigned r = u + 0x7fffu + ((u >> 16) & 1u);   // RNE
    return (unsigned short)(r >> 16);
}
__device__ __forceinline__ float bf_lo(unsigned q) {
    return __builtin_bit_cast(float, q << 16);
}
__device__ __forceinline__ float bf_hi(unsigned q) {
    return __builtin_bit_cast(float, q & 0xffff0000u);
}

// ---------------------------------------------------------------------------
// K0: w1t = bf16(w1^T) [256][512];  w2t = bf16(w2^T zero-padded) [48][256]
// ---------------------------------------------------------------------------
__global__ void prep_w_kernel(const float* __restrict__ w1, const float* __restrict__ w2,
                              unsigned short* __restrict__ w1t, unsigned short* __restrict__ w2t) {
    int tid = blockIdx.x * 256 + threadIdx.x;
    if (tid < NHID * NFEAT) {
        int n = tid >> 9, k = tid & 511;
        w1t[tid] = f2bf(w1[k * NHID + n]);
    }
    int t2 = tid - NHID * NFEAT;
    if (t2 >= 0 && t2 < NC_PAD * NHID) {
        int n = t2 >> 8, k = t2 & 255;
        w2t[t2] = (n < NCLASS) ? f2bf(w2[k * NCLASS + n]) : (unsigned short)0;
    }
}

// ---------------------------------------------------------------------------
// K1: CSR row_ptr from sorted adj_rows (lower_bound per row)
// ---------------------------------------------------------------------------
__global__ void rowptr_kernel(const int* __restrict__ rows, int* __restrict__ row_ptr) {
    int r = blockIdx.x * 256 + threadIdx.x;
    if (r > N_NODES) return;
    int lo = 0, hi = NNZ_E;
    while (lo < hi) {
        int mid = (lo + hi) >> 1;
        if (rows[mid] < r) lo = mid + 1; else hi = mid;
    }
    row_ptr[r] = lo;
}

// ---------------------------------------------------------------------------
// K2: XW = x @ w1  (bf16 MFMA, fp32 acc) -> xw bf16 [N,256]
// ---------------------------------------------------------------------------
__global__ __launch_bounds__(256) void gemm1_kernel(const float* __restrict__ x,
                                                    const unsigned short* __restrict__ w1t,
                                                    unsigned short* __restrict__ xw) {
    __shared__ unsigned short As[64][40];
    __shared__ unsigned short Bs[256][40];

    const int rb   = blockIdx.x * 64;
    const int tid  = threadIdx.x;
    const int wave = tid >> 6;
    const int lane = tid & 63;
    const int l15  = lane & 15;
    const int quad = lane >> 4;

    f32x4 acc[4][4] = {};

    int ar = tid >> 2;
    int ako = (tid & 3) * 8;
    int arow = rb + ar; if (arow >= N_NODES) arow = N_NODES - 1;
    const float* asrc_base = x + (long)arow * NFEAT + ako;

    for (int kc = 0; kc < NFEAT; kc += 32) {
        {
            const float* s = asrc_base + kc;
            float4 f0 = *(const float4*)(s);
            float4 f1 = *(const float4*)(s + 4);
            ushort8 v;
            v[0] = f2bf(f0.x); v[1] = f2bf(f0.y); v[2] = f2bf(f0.z); v[3] = f2bf(f0.w);
            v[4] = f2bf(f1.x); v[5] = f2bf(f1.y); v[6] = f2bf(f1.z); v[7] = f2bf(f1.w);
            *(ushort8*)&As[ar][ako] = v;
        }
        {
            const ushort8* s = (const ushort8*)(w1t + (long)tid * NFEAT + kc);
            *(ushort8*)&Bs[tid][0]  = s[0];
            *(ushort8*)&Bs[tid][8]  = s[1];
            *(ushort8*)&Bs[tid][16] = s[2];
            *(ushort8*)&Bs[tid][24] = s[3];
        }
        __syncthreads();

        short8 a[4];
#pragma unroll
        for (int mt = 0; mt < 4; mt++)
            a[mt] = *(const short8*)&As[mt * 16 + l15][quad * 8];
#pragma unroll
        for (int nt = 0; nt < 4; nt++) {
            short8 b = *(const short8*)&Bs[wave * 64 + nt * 16 + l15][quad * 8];
#pragma unroll
            for (int mt = 0; mt < 4; mt++)
                acc[mt][nt] = __builtin_amdgcn_mfma_f32_16x16x32_bf16(a[mt], b, acc[mt][nt], 0, 0, 0);
        }
        __syncthreads();
    }

#pragma unroll
    for (int mt = 0; mt < 4; mt++) {
#pragma unroll
        for (int nt = 0; nt < 4; nt++) {
            int col = wave * 64 + nt * 16 + l15;
#pragma unroll
            for (int r = 0; r < 4; r++) {
                int row = rb + mt * 16 + quad * 4 + r;
                if (row < N_NODES)
                    xw[(long)row * NHID + col] = f2bf(acc[mt][nt][r]);
            }
        }
    }
}

// ---------------------------------------------------------------------------
// K3: h = relu(spmm(A, xw) + b1) -> bf16 [N,256].  One wave per row.
// Unroll-8 gather for MLP (8 independent loads in flight per wave).
// ---------------------------------------------------------------------------
__global__ __launch_bounds__(256) void spmm1_kernel(const unsigned short* __restrict__ xw,
                                                    const int* __restrict__ row_ptr,
                                                    const int* __restrict__ cols,
                                                    const float* __restrict__ vals,
                                                    const float* __restrict__ b1,
                                                    unsigned short* __restrict__ h) {
    int row = blockIdx.x * 4 + (threadIdx.x >> 6);
    if (row >= N_NODES) return;
    int lane = threadIdx.x & 63;
    int e0 = row_ptr[row], e1 = row_ptr[row + 1];

    float a0 = 0.f, a1 = 0.f, a2 = 0.f, a3 = 0.f;
    for (int base = e0; base < e1; base += 64) {
        int   myc = 0;
        float myv = 0.f;
        int idx = base + lane;
        if (idx < e1) { myc = cols[idx]; myv = vals[idx]; }
        int cnt = e1 - base; if (cnt > 64) cnt = 64;
        int j = 0;
        for (; j + 8 <= cnt; j += 8) {
            int c[8]; float v[8];
#pragma unroll
            for (int u = 0; u < 8; u++) { c[u] = __shfl(myc, j + u); v[u] = __shfl(myv, j + u); }
            uint2 q[8];
#pragma unroll
            for (int u = 0; u < 8; u++) q[u] = *(const uint2*)(xw + (long)c[u] * NHID + lane * 4);
#pragma unroll
            for (int u = 0; u < 8; u++) {
                a0 += v[u] * bf_lo(q[u].x);
                a1 += v[u] * bf_hi(q[u].x);
                a2 += v[u] * bf_lo(q[u].y);
                a3 += v[u] * bf_hi(q[u].y);
            }
        }
        for (; j < cnt; j++) {
            int   c = __shfl(myc, j);
            float v = __shfl(myv, j);
            uint2 q = *(const uint2*)(xw + (long)c * NHID + lane * 4);
            a0 += v * bf_lo(q.x);
            a1 += v * bf_hi(q.x);
            a2 += v * bf_lo(q.y);
            a3 += v * bf_hi(q.y);
        }
    }
    float4 bv = *(const float4*)(b1 + lane * 4);
    a0 = fmaxf(a0 + bv.x, 0.f);
    a1 = fmaxf(a1 + bv.y, 0.f);
    a2 = fmaxf(a2 + bv.z, 0.f);
    a3 = fmaxf(a3 + bv.w, 0.f);
    uint2 o;
    o.x = (unsigned)f2bf(a0) | ((unsigned)f2bf(a1) << 16);
    o.y = (unsigned)f2bf(a2) | ((unsigned)f2bf(a3) << 16);
    *(uint2*)(h + (long)row * NHID + lane * 4) = o;
}

// ---------------------------------------------------------------------------
// K4: p = h @ w2  (bf16 MFMA) -> bf16 [N,48].  One wave per 16-row tile.
// ---------------------------------------------------------------------------
__global__ __launch_bounds__(256) void gemm2_kernel(const unsigned short* __restrict__ h,
                                                    const unsigned short* __restrict__ w2t,
                                                    unsigned short* __restrict__ p) {
    int rt = blockIdx.x * 4 + (threadIdx.x >> 6);
    int row0 = rt * 16;
    if (row0 >= N_NODES) return;
    int lane = threadIdx.x & 63;
    int l15 = lane & 15, quad = lane >> 4;

    int arow = row0 + l15; if (arow >= N_NODES) arow = N_NODES - 1;
    f32x4 acc[3] = {};
#pragma unroll
    for (int kc = 0; kc < NHID; kc += 32) {
        short8 a = *(const short8*)(h + (long)arow * NHID + kc + quad * 8);
#pragma unroll
        for (int nt = 0; nt < 3; nt++) {
            short8 b = *(const short8*)(w2t + (long)(nt * 16 + l15) * NHID + kc + quad * 8);
            acc[nt] = __builtin_amdgcn_mfma_f32_16x16x32_bf16(a, b, acc[nt], 0, 0, 0);
        }
    }
#pragma unroll
    for (int nt = 0; nt < 3; nt++) {
        int col = nt * 16 + l15;
#pragma unroll
        for (int r = 0; r < 4; r++) {
            int row = row0 + quad * 4 + r;
            if (row < N_NODES)
                p[(long)row * NC_PAD + col] = f2bf(acc[nt][r]);
        }
    }
}

// ---------------------------------------------------------------------------
// K5: out = log_softmax(spmm(A, p) + b2).  One wave per row.
// p is bf16 [N,48]. Lane = (edge_half e = lane>>5) * 32 + t (t = lane&31);
// t<24 loads a uint = cols {2t, 2t+1}. 2 edges per j-step, unroll 4 -> 8
// gathers in flight. Cross-half fold via shfl_xor(32) before softmax.
// ---------------------------------------------------------------------------
__global__ __launch_bounds__(256) void spmm2_kernel(const unsigned short* __restrict__ p,
                                                    const int* __restrict__ row_ptr,
                                                    const int* __restrict__ cols,
                                                    const float* __restrict__ vals,
                                                    const float* __restrict__ b2,
                                                    float* __restrict__ out) {
    int row = blockIdx.x * 4 + (threadIdx.x >> 6);
    if (row >= N_NODES) return;
    int lane = threadIdx.x & 63;
    int e = lane >> 5;        // which edge of the pair
    int t = lane & 31;        // col-pair index; t<24 active
    int e0 = row_ptr[row], e1 = row_ptr[row + 1];

    float acc0 = 0.f, acc1 = 0.f;
    for (int base = e0; base < e1; base += 64) {
        int   myc = 0;
        float myv = 0.f;
        int idx = base + lane;
        if (idx < e1) { myc = cols[idx]; myv = vals[idx]; }
        int cnt = e1 - base; if (cnt > 64) cnt = 64;
        int j = 0;
        for (; j + 8 <= cnt; j += 8) {
            int c[4]; float v[4];
#pragma unroll
            for (int u = 0; u < 4; u++) {
                c[u] = __shfl(myc, j + 2 * u + e);
                v[u] = __shfl(myv, j + 2 * u + e);
            }
            unsigned q[4];
#pragma unroll
            for (int u = 0; u < 4; u++)
                q[u] = (t < 24) ? *(const unsigned*)(p + (long)c[u] * NC_PAD + 2 * t) : 0u;
#pragma unroll
            for (int u = 0; u < 4; u++) {
                acc0 += v[u] * bf_lo(q[u]);
                acc1 += v[u] * bf_hi(q[u]);
            }
        }
        for (; j < cnt; j += 2) {
            if (j + e < cnt) {
                int   c = __shfl(myc, j + e);
                float v = __shfl(myv, j + e);
                unsigned q = (t < 24) ? *(const unsigned*)(p + (long)c * NC_PAD + 2 * t) : 0u;
                acc0 += v * bf_lo(q);
                acc1 += v * bf_hi(q);
            }
        }
    }
    // fold the two edge-halves: lane L (+/-) 32 hold the same col-pair
    acc0 += __shfl_xor(acc0, 32);
    acc1 += __shfl_xor(acc1, 32);

    int c0 = 2 * t, c1 = 2 * t + 1;
    float logit0 = (c0 < NCLASS) ? acc0 + b2[c0] : -__builtin_inff();
    float logit1 = (c1 < NCLASS) ? acc1 + b2[c1] : -__builtin_inff();
    float m = fmaxf(logit0, logit1);
#pragma unroll
    for (int s = 16; s; s >>= 1) m = fmaxf(m, __shfl_xor(m, s));
    float esum = ((c0 < NCLASS) ? __expf(logit0 - m) : 0.f)
               + ((c1 < NCLASS) ? __expf(logit1 - m) : 0.f);
#pragma unroll
    for (int s = 16; s; s >>= 1) esum += __shfl_xor(esum, s);
    float lse = m + __logf(esum);
    if (e == 0) {
        if (c0 < NCLASS) out[(long)row * NCLASS + c0] = logit0 - lse;
        if (c1 < NCLASS) out[(long)row * NCLASS + c1] = logit1 - lse;
    }
}

// ---------------------------------------------------------------------------
extern "C" void kernel_launch(void* const* d_in, const int* in_sizes, int n_in,
                              void* d_out, int out_size, void* d_ws, size_t ws_size,
                              hipStream_t stream) {
    const float* x        = (const float*)d_in[0];
    const int*   adj_rows = (const int*)  d_in[1];
    const int*   adj_cols = (const int*)  d_in[2];
    const float* adj_vals = (const float*)d_in[3];
    const float* w1       = (const float*)d_in[4];
    const float* b1       = (const float*)d_in[5];
    const float* w2       = (const float*)d_in[6];
    const float* b2       = (const float*)d_in[7];
    float* out = (float*)d_out;

    char* ws = (char*)d_ws;
    unsigned short* w1t     = (unsigned short*)(ws);                      // 0.25 MB
    unsigned short* w2t     = (unsigned short*)(ws + 0x40000);            // 24 KB
    int*            row_ptr = (int*)           (ws + 0x46000);            // 0.4 MB
    unsigned short* xw      = (unsigned short*)(ws + 0xA8000);            // 51.2 MB bf16 [N,256]
    unsigned short* hbuf    = (unsigned short*)(ws + 0xA8000 + 51200000L);// 51.2 MB bf16 [N,256]
    unsigned short* p       = (unsigned short*)(ws + 0xA8000);            // bf16 [N,48], aliases xw

    prep_w_kernel<<<(NHID * NFEAT + NC_PAD * NHID + 255) / 256, 256, 0, stream>>>(w1, w2, w1t, w2t);
    rowptr_kernel<<<(N_NODES + 1 + 255) / 256, 256, 0, stream>>>(adj_rows, row_ptr);
    gemm1_kernel<<<(N_NODES + 63) / 64, 256, 0, stream>>>(x, w1t, xw);
    spmm1_kernel<<<(N_NODES + 3) / 4, 256, 0, stream>>>(xw, row_ptr, adj_cols, adj_vals, b1, hbuf);
    gemm2_kernel<<<((N_NODES + 15) / 16 + 3) / 4, 256, 0, stream>>>(hbuf, w2t, p);
    spmm2_kernel<<<(N_NODES + 3) / 4, 256, 0, stream>>>(p, row_ptr, adj_cols, adj_vals, b2, out);
}

// Round 3
// 593.060 us; speedup vs baseline: 1.3958x; 1.1729x over previous
//
#include <hip/hip_runtime.h>
#include <math.h>

#define N_NODES 100000
#define NNZ_E   3200000
#define NFEAT   512
#define NHID    256
#define NCLASS  41
#define NC_PAD  48     // w2t padded rows
#define P_STRIDE 64    // p row stride in bytes (fp8)

typedef __attribute__((ext_vector_type(8))) short   short8;   // 8 bf16 (4 VGPRs)
typedef __attribute__((ext_vector_type(8))) unsigned short ushort8;
typedef __attribute__((ext_vector_type(4))) float   f32x4;
typedef __attribute__((ext_vector_type(2))) float   f32x2;

// ---- bf16 helpers ----
__device__ __forceinline__ unsigned short f2bf(float f) {
    unsigned u = __builtin_bit_cast(unsigned, f);
    unsigned r = u + 0x7fffu + ((u >> 16) & 1u);   // RNE
    return (unsigned short)(r >> 16);
}
// ---- fp8 e4m3 helpers (OCP, native gfx950 cvt) ----
__device__ __forceinline__ unsigned char f2fp8(float f) {
    return (unsigned char)(__builtin_amdgcn_cvt_pk_fp8_f32(f, 0.f, 0, false) & 0xff);
}

// ---------------------------------------------------------------------------
// K0: w1t = bf16(w1^T) [256][512];  w2t = bf16(w2^T zero-padded) [48][256]
// ---------------------------------------------------------------------------
__global__ void prep_w_kernel(const float* __restrict__ w1, const float* __restrict__ w2,
                              unsigned short* __restrict__ w1t, unsigned short* __restrict__ w2t) {
    int tid = blockIdx.x * 256 + threadIdx.x;
    if (tid < NHID * NFEAT) {
        int n = tid >> 9, k = tid & 511;
        w1t[tid] = f2bf(w1[k * NHID + n]);
    }
    int t2 = tid - NHID * NFEAT;
    if (t2 >= 0 && t2 < NC_PAD * NHID) {
        int n = t2 >> 8, k = t2 & 255;
        w2t[t2] = (n < NCLASS) ? f2bf(w2[k * NCLASS + n]) : (unsigned short)0;
    }
}

// ---------------------------------------------------------------------------
// K1: CSR row_ptr from sorted adj_rows (lower_bound per row)
// ---------------------------------------------------------------------------
__global__ void rowptr_kernel(const int* __restrict__ rows, int* __restrict__ row_ptr) {
    int r = blockIdx.x * 256 + threadIdx.x;
    if (r > N_NODES) return;
    int lo = 0, hi = NNZ_E;
    while (lo < hi) {
        int mid = (lo + hi) >> 1;
        if (rows[mid] < r) lo = mid + 1; else hi = mid;
    }
    row_ptr[r] = lo;
}

// ---------------------------------------------------------------------------
// K2: XW = x @ w1  (bf16 MFMA, fp32 acc) -> xw fp8 [N,256]
// ---------------------------------------------------------------------------
__global__ __launch_bounds__(256) void gemm1_kernel(const float* __restrict__ x,
                                                    const unsigned short* __restrict__ w1t,
                                                    unsigned char* __restrict__ xw) {
    __shared__ unsigned short As[64][40];
    __shared__ unsigned short Bs[256][40];

    const int rb   = blockIdx.x * 64;
    const int tid  = threadIdx.x;
    const int wave = tid >> 6;
    const int lane = tid & 63;
    const int l15  = lane & 15;
    const int quad = lane >> 4;

    f32x4 acc[4][4] = {};

    int ar = tid >> 2;
    int ako = (tid & 3) * 8;
    int arow = rb + ar; if (arow >= N_NODES) arow = N_NODES - 1;
    const float* asrc_base = x + (long)arow * NFEAT + ako;

    for (int kc = 0; kc < NFEAT; kc += 32) {
        {
            const float* s = asrc_base + kc;
            float4 f0 = *(const float4*)(s);
            float4 f1 = *(const float4*)(s + 4);
            ushort8 v;
            v[0] = f2bf(f0.x); v[1] = f2bf(f0.y); v[2] = f2bf(f0.z); v[3] = f2bf(f0.w);
            v[4] = f2bf(f1.x); v[5] = f2bf(f1.y); v[6] = f2bf(f1.z); v[7] = f2bf(f1.w);
            *(ushort8*)&As[ar][ako] = v;
        }
        {
            const ushort8* s = (const ushort8*)(w1t + (long)tid * NFEAT + kc);
            *(ushort8*)&Bs[tid][0]  = s[0];
            *(ushort8*)&Bs[tid][8]  = s[1];
            *(ushort8*)&Bs[tid][16] = s[2];
            *(ushort8*)&Bs[tid][24] = s[3];
        }
        __syncthreads();

        short8 a[4];
#pragma unroll
        for (int mt = 0; mt < 4; mt++)
            a[mt] = *(const short8*)&As[mt * 16 + l15][quad * 8];
#pragma unroll
        for (int nt = 0; nt < 4; nt++) {
            short8 b = *(const short8*)&Bs[wave * 64 + nt * 16 + l15][quad * 8];
#pragma unroll
            for (int mt = 0; mt < 4; mt++)
                acc[mt][nt] = __builtin_amdgcn_mfma_f32_16x16x32_bf16(a[mt], b, acc[mt][nt], 0, 0, 0);
        }
        __syncthreads();
    }

#pragma unroll
    for (int mt = 0; mt < 4; mt++) {
#pragma unroll
        for (int nt = 0; nt < 4; nt++) {
            int col = wave * 64 + nt * 16 + l15;
#pragma unroll
            for (int r = 0; r < 4; r++) {
                int row = rb + mt * 16 + quad * 4 + r;
                if (row < N_NODES)
                    xw[(long)row * NHID + col] = f2fp8(acc[mt][nt][r]);
            }
        }
    }
}

// ---------------------------------------------------------------------------
// K3: h = relu(spmm(A, xw) + b1) -> bf16 [N,256].  One wave per row.
// xw is fp8: lane covers cols 4*lane..4*lane+3, one uint gather per edge.
// ---------------------------------------------------------------------------
__global__ __launch_bounds__(256) void spmm1_kernel(const unsigned char* __restrict__ xw,
                                                    const int* __restrict__ row_ptr,
                                                    const int* __restrict__ cols,
                                                    const float* __restrict__ vals,
                                                    const float* __restrict__ b1,
                                                    unsigned short* __restrict__ h) {
    int row = blockIdx.x * 4 + (threadIdx.x >> 6);
    if (row >= N_NODES) return;
    int lane = threadIdx.x & 63;
    int e0 = row_ptr[row], e1 = row_ptr[row + 1];

    float a0 = 0.f, a1 = 0.f, a2 = 0.f, a3 = 0.f;
    for (int base = e0; base < e1; base += 64) {
        int   myc = 0;
        float myv = 0.f;
        int idx = base + lane;
        if (idx < e1) { myc = cols[idx]; myv = vals[idx]; }
        int cnt = e1 - base; if (cnt > 64) cnt = 64;
        int j = 0;
        for (; j + 8 <= cnt; j += 8) {
            int c[8]; float v[8];
#pragma unroll
            for (int u = 0; u < 8; u++) { c[u] = __shfl(myc, j + u); v[u] = __shfl(myv, j + u); }
            unsigned q[8];
#pragma unroll
            for (int u = 0; u < 8; u++) q[u] = *(const unsigned*)(xw + (long)c[u] * NHID + lane * 4);
#pragma unroll
            for (int u = 0; u < 8; u++) {
                f32x2 lo = __builtin_amdgcn_cvt_pk_f32_fp8((int)q[u], false);
                f32x2 hi = __builtin_amdgcn_cvt_pk_f32_fp8((int)q[u], true);
                a0 += v[u] * lo[0];
                a1 += v[u] * lo[1];
                a2 += v[u] * hi[0];
                a3 += v[u] * hi[1];
            }
        }
        for (; j < cnt; j++) {
            int   c = __shfl(myc, j);
            float v = __shfl(myv, j);
            unsigned q = *(const unsigned*)(xw + (long)c * NHID + lane * 4);
            f32x2 lo = __builtin_amdgcn_cvt_pk_f32_fp8((int)q, false);
            f32x2 hi = __builtin_amdgcn_cvt_pk_f32_fp8((int)q, true);
            a0 += v * lo[0];
            a1 += v * lo[1];
            a2 += v * hi[0];
            a3 += v * hi[1];
        }
    }
    float4 bv = *(const float4*)(b1 + lane * 4);
    a0 = fmaxf(a0 + bv.x, 0.f);
    a1 = fmaxf(a1 + bv.y, 0.f);
    a2 = fmaxf(a2 + bv.z, 0.f);
    a3 = fmaxf(a3 + bv.w, 0.f);
    uint2 o;
    o.x = (unsigned)f2bf(a0) | ((unsigned)f2bf(a1) << 16);
    o.y = (unsigned)f2bf(a2) | ((unsigned)f2bf(a3) << 16);
    *(uint2*)(h + (long)row * NHID + lane * 4) = o;
}

// ---------------------------------------------------------------------------
// K4: p = h @ w2  (bf16 MFMA) -> fp8 [N, P_STRIDE=64] (cols 0..47 written)
// ---------------------------------------------------------------------------
__global__ __launch_bounds__(256) void gemm2_kernel(const unsigned short* __restrict__ h,
                                                    const unsigned short* __restrict__ w2t,
                                                    unsigned char* __restrict__ p) {
    int rt = blockIdx.x * 4 + (threadIdx.x >> 6);
    int row0 = rt * 16;
    if (row0 >= N_NODES) return;
    int lane = threadIdx.x & 63;
    int l15 = lane & 15, quad = lane >> 4;

    int arow = row0 + l15; if (arow >= N_NODES) arow = N_NODES - 1;
    f32x4 acc[3] = {};
#pragma unroll
    for (int kc = 0; kc < NHID; kc += 32) {
        short8 a = *(const short8*)(h + (long)arow * NHID + kc + quad * 8);
#pragma unroll
        for (int nt = 0; nt < 3; nt++) {
            short8 b = *(const short8*)(w2t + (long)(nt * 16 + l15) * NHID + kc + quad * 8);
            acc[nt] = __builtin_amdgcn_mfma_f32_16x16x32_bf16(a, b, acc[nt], 0, 0, 0);
        }
    }
#pragma unroll
    for (int nt = 0; nt < 3; nt++) {
        int col = nt * 16 + l15;
#pragma unroll
        for (int r = 0; r < 4; r++) {
            int row = row0 + quad * 4 + r;
            if (row < N_NODES)
                p[(long)row * P_STRIDE + col] = f2fp8(acc[nt][r]);
        }
    }
}

// ---------------------------------------------------------------------------
// K5: out = log_softmax(spmm(A, p) + b2).  One wave per row.
// p is fp8, 64 B rows. e = lane>>5 (edge of pair), t = lane&31;
// t<12 loads uint = cols {4t..4t+3}. 2 edges/j-step, unroll 4.
// ---------------------------------------------------------------------------
__global__ __launch_bounds__(256) void spmm2_kernel(const unsigned char* __restrict__ p,
                                                    const int* __restrict__ row_ptr,
                                                    const int* __restrict__ cols,
                                                    const float* __restrict__ vals,
                                                    const float* __restrict__ b2,
                                                    float* __restrict__ out) {
    int row = blockIdx.x * 4 + (threadIdx.x >> 6);
    if (row >= N_NODES) return;
    int lane = threadIdx.x & 63;
    int e = lane >> 5;
    int t = lane & 31;
    int e0 = row_ptr[row], e1 = row_ptr[row + 1];

    float a0 = 0.f, a1 = 0.f, a2 = 0.f, a3 = 0.f;
    for (int base = e0; base < e1; base += 64) {
        int   myc = 0;
        float myv = 0.f;
        int idx = base + lane;
        if (idx < e1) { myc = cols[idx]; myv = vals[idx]; }
        int cnt = e1 - base; if (cnt > 64) cnt = 64;
        int j = 0;
        for (; j + 8 <= cnt; j += 8) {
            int c[4]; float v[4];
#pragma unroll
            for (int u = 0; u < 4; u++) {
                c[u] = __shfl(myc, j + 2 * u + e);
                v[u] = __shfl(myv, j + 2 * u + e);
            }
            unsigned q[4];
#pragma unroll
            for (int u = 0; u < 4; u++)
                q[u] = (t < 12) ? *(const unsigned*)(p + (long)c[u] * P_STRIDE + 4 * t) : 0u;
#pragma unroll
            for (int u = 0; u < 4; u++) {
                f32x2 lo = __builtin_amdgcn_cvt_pk_f32_fp8((int)q[u], false);
                f32x2 hi = __builtin_amdgcn_cvt_pk_f32_fp8((int)q[u], true);
                a0 += v[u] * lo[0];
                a1 += v[u] * lo[1];
                a2 += v[u] * hi[0];
                a3 += v[u] * hi[1];
            }
        }
        for (; j < cnt; j += 2) {
            int jj = j + e;
            int jc = jj < cnt ? jj : cnt - 1;       // uniform-exec tail
            int   c = __shfl(myc, jc);
            float v = __shfl(myv, jc);
            if (jj >= cnt) v = 0.f;
            unsigned q = (t < 12) ? *(const unsigned*)(p + (long)c * P_STRIDE + 4 * t) : 0u;
            f32x2 lo = __builtin_amdgcn_cvt_pk_f32_fp8((int)q, false);
            f32x2 hi = __builtin_amdgcn_cvt_pk_f32_fp8((int)q, true);
            a0 += v * lo[0];
            a1 += v * lo[1];
            a2 += v * hi[0];
            a3 += v * hi[1];
        }
    }
    // fold the two edge-halves
    a0 += __shfl_xor(a0, 32);
    a1 += __shfl_xor(a1, 32);
    a2 += __shfl_xor(a2, 32);
    a3 += __shfl_xor(a3, 32);

    int c0 = 4 * t, c1 = 4 * t + 1, c2 = 4 * t + 2, c3 = 4 * t + 3;
    float l0 = (c0 < NCLASS) ? a0 + b2[c0] : -__builtin_inff();
    float l1 = (c1 < NCLASS) ? a1 + b2[c1] : -__builtin_inff();
    float l2 = (c2 < NCLASS) ? a2 + b2[c2] : -__builtin_inff();
    float l3 = (c3 < NCLASS) ? a3 + b2[c3] : -__builtin_inff();
    float m = fmaxf(fmaxf(l0, l1), fmaxf(l2, l3));
#pragma unroll
    for (int s = 16; s; s >>= 1) m = fmaxf(m, __shfl_xor(m, s));
    float esum = ((c0 < NCLASS) ? __expf(l0 - m) : 0.f)
               + ((c1 < NCLASS) ? __expf(l1 - m) : 0.f)
               + ((c2 < NCLASS) ? __expf(l2 - m) : 0.f)
               + ((c3 < NCLASS) ? __expf(l3 - m) : 0.f);
#pragma unroll
    for (int s = 16; s; s >>= 1) esum += __shfl_xor(esum, s);
    float lse = m + __logf(esum);
    if (e == 0) {
        long ob = (long)row * NCLASS;
        if (c0 < NCLASS) out[ob + c0] = l0 - lse;
        if (c1 < NCLASS) out[ob + c1] = l1 - lse;
        if (c2 < NCLASS) out[ob + c2] = l2 - lse;
        if (c3 < NCLASS) out[ob + c3] = l3 - lse;
    }
}

// ---------------------------------------------------------------------------
extern "C" void kernel_launch(void* const* d_in, const int* in_sizes, int n_in,
                              void* d_out, int out_size, void* d_ws, size_t ws_size,
                              hipStream_t stream) {
    const float* x        = (const float*)d_in[0];
    const int*   adj_rows = (const int*)  d_in[1];
    const int*   adj_cols = (const int*)  d_in[2];
    const float* adj_vals = (const float*)d_in[3];
    const float* w1       = (const float*)d_in[4];
    const float* b1       = (const float*)d_in[5];
    const float* w2       = (const float*)d_in[6];
    const float* b2       = (const float*)d_in[7];
    float* out = (float*)d_out;

    char* ws = (char*)d_ws;
    unsigned short* w1t     = (unsigned short*)(ws);                       // 0.25 MB
    unsigned short* w2t     = (unsigned short*)(ws + 0x40000);             // 24 KB
    int*            row_ptr = (int*)           (ws + 0x46000);             // 0.4 MB
    unsigned char*  xw      = (unsigned char*) (ws + 0xA8000);             // 25.6 MB fp8 [N,256]
    unsigned short* hbuf    = (unsigned short*)(ws + 0xA8000 + 25600000L); // 51.2 MB bf16 [N,256]
    unsigned char*  p       = (unsigned char*) (ws + 0xA8000);             // 6.4 MB fp8 [N,64], aliases xw

    prep_w_kernel<<<(NHID * NFEAT + NC_PAD * NHID + 255) / 256, 256, 0, stream>>>(w1, w2, w1t, w2t);
    rowptr_kernel<<<(N_NODES + 1 + 255) / 256, 256, 0, stream>>>(adj_rows, row_ptr);
    gemm1_kernel<<<(N_NODES + 63) / 64, 256, 0, stream>>>(x, w1t, xw);
    spmm1_kernel<<<(N_NODES + 3) / 4, 256, 0, stream>>>(xw, row_ptr, adj_cols, adj_vals, b1, hbuf);
    gemm2_kernel<<<((N_NODES + 15) / 16 + 3) / 4, 256, 0, stream>>>(hbuf, w2t, p);
    spmm2_kernel<<<(N_NODES + 3) / 4, 256, 0, stream>>>(p, row_ptr, adj_cols, adj_vals, b2, out);
}